// Round 1
// baseline (59.558 us; speedup 1.0000x reference)
//
#include <hip/hip_runtime.h>

#define BATCH 256
#define KDIM 1024
#define NFEAT 64
#define KD 16
#define NCOL (NFEAT * KD)  // 1024

// ---------------------------------------------------------------------------
// Kernel 1: M = x @ T   (256x1024 @ 1024x1024 -> 256x1024, fp32)
// grid 256: f = b>>2 (feature, 16 cols), q = b&3 (row quarter, 64 rows)
// block 256: r = tid&63 (row), cg = tid>>6 (col group of 4)
// x tile staged in LDS (64 rows x 256 K) with XOR swizzle on 16B chunks so the
// column-read (lanes = rows, stride 1KB) is bank-conflict-free.
// ---------------------------------------------------------------------------
__global__ __launch_bounds__(256) void md_gemm(const float* __restrict__ x,
                                               const float* __restrict__ T,
                                               float* __restrict__ M) {
  __shared__ float xs[64 * 256];  // 64 KB
  const int tid = threadIdx.x;
  const int f = blockIdx.x >> 2;
  const int q = blockIdx.x & 3;
  const int r = tid & 63;
  const int cg = tid >> 6;
  const int col0 = f * KD + cg * 4;

  float acc0 = 0.f, acc1 = 0.f, acc2 = 0.f, acc3 = 0.f;
  const float4* x4 = (const float4*)x;

  for (int kt = 0; kt < KDIM; kt += 256) {
    __syncthreads();
    // stage x[q*64 .. +63][kt .. kt+255], 16 float4 per thread, coalesced
#pragma unroll
    for (int n = 0; n < 16; ++n) {
      int flat = n * 256 + tid;   // 0..4095
      int row = flat >> 6;        // 0..63
      int c4 = flat & 63;         // 16B-chunk index 0..63
      float4 v = x4[(size_t)(q * 64 + row) * (KDIM / 4) + (kt >> 2) + c4];
      int sc = c4 ^ (row & 7);    // XOR swizzle
      *(float4*)&xs[row * 256 + sc * 4] = v;
    }
    __syncthreads();

    const float* Tp = T + (size_t)kt * NCOL + col0;
#pragma unroll 4
    for (int c = 0; c < 64; ++c) {
      float4 xv = *(const float4*)&xs[r * 256 + ((c ^ (r & 7)) << 2)];
      float xk[4] = {xv.x, xv.y, xv.z, xv.w};
#pragma unroll
      for (int e = 0; e < 4; ++e) {
        float4 tv = *(const float4*)(Tp + (size_t)(c * 4 + e) * NCOL);
        acc0 = fmaf(xk[e], tv.x, acc0);
        acc1 = fmaf(xk[e], tv.y, acc1);
        acc2 = fmaf(xk[e], tv.z, acc2);
        acc3 = fmaf(xk[e], tv.w, acc3);
      }
    }
  }
  const int i = q * 64 + r;
  float4 res = {acc0, acc1, acc2, acc3};
  *(float4*)&M[(size_t)i * NCOL + col0] = res;
}

// ---------------------------------------------------------------------------
// Kernel 2: out[i,f] = sum_j exp(-sum_k |M[i,f,k]-M[j,f,k]|) - 1
// grid 512: f = b>>3, j-tile jt = b&7 (32 j's). block 256 threads = i.
// j-tile staged in LDS (broadcast reads). Self term cancelled by acc = -1 in
// the tile that contains j == i (|m-m| = 0 -> exp(0) = 1 exactly).
// Partial sums combined with atomicAdd (out zeroed by memset beforehand).
// ---------------------------------------------------------------------------
__global__ __launch_bounds__(256) void md_pairwise(const float* __restrict__ M,
                                                   float* __restrict__ out) {
  __shared__ float ms[32 * KD];  // 2 KB
  const int tid = threadIdx.x;
  const int f = blockIdx.x >> 3;
  const int jt = blockIdx.x & 7;
  const int j0 = jt * 32;

  if (tid < 128) {
    int j = tid >> 2;
    int kc = tid & 3;
    float4 v = *(const float4*)&M[(size_t)(j0 + j) * NCOL + f * KD + kc * 4];
    *(float4*)&ms[j * KD + kc * 4] = v;
  }

  float m[KD];
#pragma unroll
  for (int kc = 0; kc < 4; ++kc) {
    float4 v = *(const float4*)&M[(size_t)tid * NCOL + f * KD + kc * 4];
    m[kc * 4 + 0] = v.x;
    m[kc * 4 + 1] = v.y;
    m[kc * 4 + 2] = v.z;
    m[kc * 4 + 3] = v.w;
  }
  __syncthreads();

  float acc = ((tid >> 5) == jt) ? -1.0f : 0.0f;
#pragma unroll 4
  for (int j = 0; j < 32; ++j) {
    float l1 = 0.f;
#pragma unroll
    for (int k = 0; k < KD; ++k) l1 += fabsf(m[k] - ms[j * KD + k]);
    acc += __expf(-l1);
  }
  atomicAdd(&out[(size_t)tid * NFEAT + f], acc);
}

extern "C" void kernel_launch(void* const* d_in, const int* in_sizes, int n_in,
                              void* d_out, int out_size, void* d_ws, size_t ws_size,
                              hipStream_t stream) {
  const float* x = (const float*)d_in[0];
  const float* T = (const float*)d_in[1];
  float* out = (float*)d_out;
  float* M = (float*)d_ws;  // 256*1024 f32 = 1 MB scratch

  hipMemsetAsync(out, 0, (size_t)BATCH * NFEAT * sizeof(float), stream);
  md_gemm<<<256, 256, 0, stream>>>(x, T, M);
  md_pairwise<<<512, 256, 0, stream>>>(M, out);
}